// Round 1
// 465.194 us; speedup vs baseline: 1.0355x; 1.0355x over previous
//
#include <hip/hip_runtime.h>
#include <hip/hip_bf16.h>
#include <cstdint>
#include <cstddef>

// ---------------------------------------------------------------------------
// EinsteinCore: hyperbolic attention, MI355X fp16-MFMA implementation.
// B=8, S=M=2048, K_in=1024, DH=DOUT=512, k=1 (sk=1), beta=1/sqrt(512).
//
// Math identities used (k=1):
//   Q0=cosh(th), Qs=f*x with f=sinh(th)*s/vn, s=min(3.5/(n+1e-7),1), th=vn=max(n*s,eps)
//   gamma*v_klein = Vs, gamma = V0  => mid = (sum p*Vs)/(sum p*V0), p unnormalized
//   p = (x+sqrt(x^2-1))^(-beta),  x = Q0*K0 - f_q*f_k*(xq . xk)  in [1, ~548]
//   out = d0 * mid/||mid||  (clip scale cancels), d0 = arccosh(max(z0,1+1e-7))
// ---------------------------------------------------------------------------

typedef _Float16 f16x8 __attribute__((ext_vector_type(8)));
typedef _Float16 f16x4 __attribute__((ext_vector_type(4)));
typedef float    f32x4 __attribute__((ext_vector_type(4)));

#define BETA_F 0.04419417382415922f
#define LOG2E_F 1.4426950408889634f
#define LN2_F 0.6931471805599453f

__device__ __forceinline__ void gload_lds16(const void* g, void* l) {
  __builtin_amdgcn_global_load_lds(
      (__attribute__((address_space(1))) void*)(g),
      (__attribute__((address_space(3))) void*)(l), 16, 0, 0);
}

// ---------------------------------------------------------------------------
// K1: fused projection GEMM.  proj[r][d] = sum_k X[r][k]*W[d][k] + b[d]
// r in [0,49152): rows 0..16383 = queries, 16384.. = keys, 32768.. = values.
// 128x128 tile, BK=32, 256 threads (4 waves, 64x64 quadrant per wave).
// ---------------------------------------------------------------------------
#define K1_PIT 40   // f16 LDS pitch (80B: 16B-aligned frags, 2-way banks = free)

__global__ __launch_bounds__(256) void k_proj(
    const float* __restrict__ xq, const float* __restrict__ xk, const float* __restrict__ xv,
    const float* __restrict__ wq, const float* __restrict__ wk, const float* __restrict__ wv,
    const float* __restrict__ bq, const float* __restrict__ bk, const float* __restrict__ bv,
    _Float16* __restrict__ proj)
{
  __shared__ __align__(16) _Float16 As[128 * K1_PIT];
  __shared__ __align__(16) _Float16 Bs[128 * K1_PIT];

  const int tid = threadIdx.x;
  const int w = tid >> 6, l = tid & 63, ln = l & 15, q = l >> 4;
  const int wm = w & 1, wn = w >> 1;
  const int r0 = blockIdx.y * 128;        // global output row base (0..49151)
  const int n0 = blockIdx.x * 128;        // output col base (0..511)
  const int which = r0 >> 14;             // 0=q,1=k,2=v (blocks never straddle)
  const int rloc = r0 & 16383;
  const float* X = (which == 0) ? xq : ((which == 1) ? xk : xv);
  const float* W = (which == 0) ? wq : ((which == 1) ? wk : wv);
  const float* bias = (which == 0) ? bq : ((which == 1) ? bk : bv);

  f32x4 acc[4][4];
#pragma unroll
  for (int mt = 0; mt < 4; ++mt)
#pragma unroll
    for (int nt = 0; nt < 4; ++nt) acc[mt][nt] = f32x4{0.f, 0.f, 0.f, 0.f};

  for (int kk = 0; kk < 1024; kk += 32) {
    __syncthreads();
#pragma unroll
    for (int it = 0; it < 4; ++it) {
      int v = tid + 256 * it;
      int row = v >> 3, c4 = v & 7;       // 8 float4 per 32-wide row
      float4 a = *(const float4*)(X + (size_t)(rloc + row) * 1024 + kk + c4 * 4);
      float4 b = *(const float4*)(W + (size_t)(n0 + row) * 1024 + kk + c4 * 4);
      f16x4 ah = { (_Float16)a.x, (_Float16)a.y, (_Float16)a.z, (_Float16)a.w };
      f16x4 bh = { (_Float16)b.x, (_Float16)b.y, (_Float16)b.z, (_Float16)b.w };
      *(f16x4*)&As[row * K1_PIT + c4 * 4] = ah;
      *(f16x4*)&Bs[row * K1_PIT + c4 * 4] = bh;
    }
    __syncthreads();

    f16x8 af[4], bf[4];
#pragma unroll
    for (int mt = 0; mt < 4; ++mt)
      af[mt] = *(const f16x8*)&As[(wm * 64 + mt * 16 + ln) * K1_PIT + q * 8];
#pragma unroll
    for (int nt = 0; nt < 4; ++nt)
      bf[nt] = *(const f16x8*)&Bs[(wn * 64 + nt * 16 + ln) * K1_PIT + q * 8];
#pragma unroll
    for (int mt = 0; mt < 4; ++mt)
#pragma unroll
      for (int nt = 0; nt < 4; ++nt)
        acc[mt][nt] = __builtin_amdgcn_mfma_f32_16x16x32_f16(af[mt], bf[nt], acc[mt][nt], 0, 0, 0);
  }

  float bl[4];
#pragma unroll
  for (int nt = 0; nt < 4; ++nt) bl[nt] = bias[n0 + wn * 64 + nt * 16 + ln];
#pragma unroll
  for (int mt = 0; mt < 4; ++mt)
#pragma unroll
    for (int nt = 0; nt < 4; ++nt)
#pragma unroll
      for (int i = 0; i < 4; ++i) {
        int r = r0 + wm * 64 + mt * 16 + q * 4 + i;
        int c = n0 + wn * 64 + nt * 16 + ln;
        proj[(size_t)r * 512 + c] = (_Float16)(acc[mt][nt][i] + bl[nt]);
      }
}

// ---------------------------------------------------------------------------
// K2a: per-row expmap scalars.  f[r] = sinh(th)*s/vn,  c0[r] = cosh(th).
// One wave per row (512 elems = 8/lane).
// ---------------------------------------------------------------------------
__global__ __launch_bounds__(256) void k_rowstats(
    const _Float16* __restrict__ proj, float* __restrict__ fs, float* __restrict__ c0)
{
  const int w = threadIdx.x >> 6, l = threadIdx.x & 63;
  const int r = blockIdx.x * 4 + w;
  const f16x8 v = *(const f16x8*)(proj + (size_t)r * 512 + l * 8);
  float ss = 0.f;
#pragma unroll
  for (int j = 0; j < 8; ++j) { float x = (float)v[j]; ss += x * x; }
#pragma unroll
  for (int m = 1; m < 64; m <<= 1) ss += __shfl_xor(ss, m, 64);
  if (l == 0) {
    float n = sqrtf(ss);
    float s = fminf(3.5f / (n + 1e-7f), 1.0f);
    float vn = fmaxf(n * s, 1e-12f);
    float e = __builtin_amdgcn_exp2f(vn * LOG2E_F);
    float ie = 1.0f / e;
    c0[r] = 0.5f * (e + ie);
    fs[r] = 0.5f * (e - ie) * s / vn;
  }
}

// ---------------------------------------------------------------------------
// K2b: transpose V-projection to xvT[b][d][m] (m-contiguous for PV B-frags).
// 64x64 tiles through LDS.
// ---------------------------------------------------------------------------
#define K2_TP 72   // ushort pitch (144B rows)

__global__ __launch_bounds__(256) void k_transpose_v(
    const _Float16* __restrict__ proj, _Float16* __restrict__ xvT)
{
  __shared__ __align__(16) unsigned short t[64 * K2_TP];
  const int b = blockIdx.z, m0 = blockIdx.x * 64, d0 = blockIdx.y * 64;
  const unsigned short* pv =
      (const unsigned short*)(proj + (size_t)(32768 + b * 2048 + m0) * 512);
#pragma unroll
  for (int it = 0; it < 2; ++it) {
    int v = threadIdx.x + 256 * it;
    int r = v >> 3, c4 = v & 7;
    uint4 dd = *(const uint4*)(pv + (size_t)r * 512 + d0 + c4 * 8);
    *(uint4*)&t[r * K2_TP + c4 * 8] = dd;
  }
  __syncthreads();
#pragma unroll
  for (int it = 0; it < 2; ++it) {
    int v = threadIdx.x + 256 * it;
    int dr = v >> 3, mc = v & 7;
    unsigned int o[4];
#pragma unroll
    for (int jj = 0; jj < 4; ++jj) {
      unsigned int lo = t[(mc * 8 + jj * 2) * K2_TP + dr];
      unsigned int hi = t[(mc * 8 + jj * 2 + 1) * K2_TP + dr];
      o[jj] = lo | (hi << 16);
    }
    uint4 dd = { o[0], o[1], o[2], o[3] };
    unsigned short* dst =
        (unsigned short*)(xvT + ((size_t)b * 512 + d0 + dr) * 2048 + m0 + mc * 8);
    *(uint4*)dst = dd;
  }
}

// ---------------------------------------------------------------------------
// K3: fused hyperbolic attention — double-buffered pipelined schedule.
// Block = (b, 32 s-rows), 256 threads (4 waves).  m-tiles of 32.
// Wave roles QK: rh=w>>1 (s half), ch=w&1 (m half).  PV: wave owns d-chunk w*128.
// K-tiles live in KA (32KB), V-tiles in KB (32KB).  2 barriers per tile:
//   sync#1: KA=K[t] visible / PV[t-1] done with KB,P
//     issue V[t]->KB ; QK on KA ; epilogue -> P        (V latency under QK)
//   sync#2: KB=V[t] visible / KA reads + P writes done
//     issue K[t+1]->KA ; PV on KB                      (K latency under PV)
// No barrier ever drains a load issued in the same phase.
// global_load_lds(16B) with XOR-swizzled gptrs for conflict-free ds_read_b128.
// ---------------------------------------------------------------------------
__global__ __launch_bounds__(256, 2) void k_attn(
    const _Float16* __restrict__ proj, const _Float16* __restrict__ xvT,
    const float* __restrict__ fs, const float* __restrict__ c0,
    float* __restrict__ out)
{
  __shared__ __align__(16) _Float16 KA[16384];     // 32 KB: K tile [32 m][512 k]
  __shared__ __align__(16) _Float16 KB[16384];     // 32 KB: V tile [512 d][32 m]
  __shared__ __align__(16) _Float16 P[32 * 40];    // p*f_v tile, pitch 40 (80B)
  __shared__ float s_den[2][32];
  __shared__ float s_mn2[4][32];
  __shared__ float s_g[32];

  const int tid = threadIdx.x;
  const int w = tid >> 6, l = tid & 63, ln = l & 15, q = l >> 4;
  const int rh = w >> 1, ch = w & 1;
  const int b = blockIdx.y;
  const int s0 = blockIdx.x * 32;

  const _Float16* projq = proj + (size_t)(b * 2048 + s0) * 512;
  const _Float16* projk = proj + (size_t)(16384 + b * 2048) * 512;
  const _Float16* vt = xvT + (size_t)b * 512 * 2048;
  const float* fqp = fs + b * 2048 + s0;
  const float* fkp = fs + 16384 + b * 2048;
  const float* fvp = fs + 32768 + b * 2048;
  const float* cqp = c0 + b * 2048 + s0;
  const float* ckp = c0 + 16384 + b * 2048;
  const float* cvp = c0 + 32768 + b * 2048;

  // --- prologue: stage K[0] into KA first so its latency overlaps Q loads ---
#pragma unroll
  for (int rr = 0; rr < 8; ++rr) {
    int mloc = w * 8 + rr;
    const _Float16* g = projk + (size_t)mloc * 512 + ((l ^ (mloc & 7)) * 8);
    gload_lds16(g, &KA[mloc * 512]);
  }

  // Q fragments resident in registers: rows rh*16+ln, all 512 k.
  f16x8 qf[16];
  {
    const _Float16* qrow = projq + (size_t)(rh * 16 + ln) * 512;
#pragma unroll
    for (int kc = 0; kc < 16; ++kc) qf[kc] = *(const f16x8*)(qrow + kc * 32 + q * 8);
  }
  float cq_i[4], fq_i[4];
#pragma unroll
  for (int i = 0; i < 4; ++i) {
    cq_i[i] = cqp[rh * 16 + q * 4 + i];
    fq_i[i] = fqp[rh * 16 + q * 4 + i];
  }
  // tile-0 per-lane K/V row scalars
  const int mll = ch * 16 + ln;
  float ck_c = ckp[mll], fk_c = fkp[mll], fv_c = fvp[mll], cv_c = cvp[mll];

  f32x4 acc[2][8];
#pragma unroll
  for (int rt = 0; rt < 2; ++rt)
#pragma unroll
    for (int nt = 0; nt < 8; ++nt) acc[rt][nt] = f32x4{0.f, 0.f, 0.f, 0.f};
  float den_acc[4] = {0.f, 0.f, 0.f, 0.f};

  for (int m0 = 0; m0 < 2048; m0 += 32) {
    __syncthreads();                             // KA=K[t] visible; PV[t-1] done w/ KB,P
    // --- issue V[t] stage into KB: [d 0..511][m 0..31], 16 d-rows/instr ---
#pragma unroll
    for (int uu = 0; uu < 8; ++uu) {
      int u = w * 8 + uu;
      int dloc = u * 16 + (l >> 2);
      int cg = (l & 3) ^ ((dloc >> 1) & 3);
      const _Float16* g = vt + (size_t)dloc * 2048 + m0 + cg * 8;
      gload_lds16(g, &KB[u * 512]);
    }
    // --- prefetch next-tile per-lane scalars (drain at sync#2, under QK) ---
    float ck_n = 0.f, fk_n = 0.f, fv_n = 0.f, cv_n = 0.f;
    if (m0 + 32 < 2048) {
      int mn = m0 + 32 + ch * 16 + ln;
      ck_n = ckp[mn]; fk_n = fkp[mn]; fv_n = fvp[mn]; cv_n = cvp[mn];
    }

    // --- QK: P-quarter (rh, ch), K=512, on KA ---
    f32x4 pacc = f32x4{0.f, 0.f, 0.f, 0.f};
    {
      const _Float16* krow = &KA[(ch * 16 + ln) * 512];
      const int msw = (ch * 16 + ln) & 7;
#pragma unroll
      for (int kc = 0; kc < 16; ++kc) {
        f16x8 kf = *(const f16x8*)(krow + (((kc * 4 + q) ^ msw) * 8));
        pacc = __builtin_amdgcn_mfma_f32_16x16x32_f16(qf[kc], kf, pacc, 0, 0, 0);
      }
    }
    // --- score epilogue: p = (x+sqrt(x^2-1))^(-beta) ---
#pragma unroll
    for (int i = 0; i < 4; ++i) {
      float x = cq_i[i] * ck_c - (fq_i[i] * fk_c) * pacc[i];
      x = fmaxf(x, 1.0f + 1e-7f);
      float r_ = x + __builtin_amdgcn_sqrtf(x * x - 1.0f);
      float p = __builtin_amdgcn_exp2f(-BETA_F * __builtin_amdgcn_logf(r_));
      den_acc[i] += p * cv_c;
      P[(rh * 16 + q * 4 + i) * 40 + ch * 16 + ln] = (_Float16)(p * fv_c);
    }
    __syncthreads();                             // KB=V[t] visible; KA dead; P visible
    // --- issue K[t+1] stage into KA (drains at next sync#1, under PV) ---
    if (m0 + 32 < 2048) {
#pragma unroll
      for (int rr = 0; rr < 8; ++rr) {
        int mloc = w * 8 + rr;
        const _Float16* g = projk + (size_t)(m0 + 32 + mloc) * 512 + ((l ^ (mloc & 7)) * 8);
        gload_lds16(g, &KA[mloc * 512]);
      }
    }
    // --- PV: num[s][d] += P[s][m] * xv[m][d], on KB ---
#pragma unroll
    for (int rt = 0; rt < 2; ++rt) {
      f16x8 pf = *(const f16x8*)&P[(rt * 16 + ln) * 40 + q * 8];
#pragma unroll
      for (int nt = 0; nt < 8; ++nt) {
        int d = w * 128 + nt * 16 + ln;
        f16x8 vf = *(const f16x8*)&KB[d * 32 + ((q ^ ((d >> 1) & 3)) * 8)];
        acc[rt][nt] = __builtin_amdgcn_mfma_f32_16x16x32_f16(pf, vf, acc[rt][nt], 0, 0, 0);
      }
    }
    ck_c = ck_n; fk_c = fk_n; fv_c = fv_n; cv_c = cv_n;
  }

  // ---- den reduction: sum over the 16 m-lanes, then over ch halves ----
#pragma unroll
  for (int i = 0; i < 4; ++i) {
    float v = den_acc[i];
    v += __shfl_xor(v, 1, 64); v += __shfl_xor(v, 2, 64);
    v += __shfl_xor(v, 4, 64); v += __shfl_xor(v, 8, 64);
    if (ln == 0) s_den[ch][rh * 16 + q * 4 + i] = v;
  }
  __syncthreads();
  if (tid < 32) {
    float dv = fmaxf(s_den[0][tid] + s_den[1][tid], 1e-12f);
    s_den[0][tid] = 1.0f / dv;                   // invden
  }
  __syncthreads();
  // ---- ||mid||^2 partials ----
#pragma unroll
  for (int rt = 0; rt < 2; ++rt)
#pragma unroll
    for (int i = 0; i < 4; ++i) {
      int s = rt * 16 + q * 4 + i;
      float inv = s_den[0][s];
      float mm = 0.f;
#pragma unroll
      for (int nt = 0; nt < 8; ++nt) {
        float mid = acc[rt][nt][i] * inv;
        mm += mid * mid;
      }
      mm += __shfl_xor(mm, 1, 64); mm += __shfl_xor(mm, 2, 64);
      mm += __shfl_xor(mm, 4, 64); mm += __shfl_xor(mm, 8, 64);
      if (ln == 0) s_mn2[w][s] = mm;
    }
  __syncthreads();
  if (tid < 32) {
    float mn2 = s_mn2[0][tid] + s_mn2[1][tid] + s_mn2[2][tid] + s_mn2[3][tid];
    float mn = sqrtf(mn2);
    float sc = (mn >= 1.0f) ? (1.0f - 1e-6f) / mn : 1.0f;
    float mn2c = fminf(mn2 * sc * sc, 1.0f - 1e-6f);
    float z0 = 1.0f / sqrtf(fmaxf(1.0f - mn2c, 1e-12f));
    float zc = fmaxf(z0, 1.0f + 1e-7f);
    float d0 = LN2_F * __builtin_amdgcn_logf(zc + __builtin_amdgcn_sqrtf(zc * zc - 1.0f));
    s_g[tid] = (d0 / fmaxf(mn, 1e-12f)) * s_den[0][tid];   // out = s_g[s] * num
  }
  __syncthreads();

  // ---- transpose 2 s-rows at a time through LDS, coalesced float4 stores ----
  float* pbuf = (float*)KA;                      // 4KB of the dead K buffer
  for (int sp = 0; sp < 16; ++sp) {
#pragma unroll
    for (int rt = 0; rt < 2; ++rt)
#pragma unroll
      for (int i = 0; i < 4; ++i) {
        int s = rt * 16 + q * 4 + i;
        if ((s >> 1) == sp) {
          float gg = s_g[s];
#pragma unroll
          for (int nt = 0; nt < 8; ++nt)
            pbuf[(s & 1) * 512 + w * 128 + nt * 16 + ln] = gg * acc[rt][nt][i];
        }
      }
    __syncthreads();
    {
      int row = tid >> 7, c4 = tid & 127;
      float4 vv = *(float4*)&pbuf[row * 512 + c4 * 4];
      *(float4*)&out[((size_t)(b * 2048 + s0 + sp * 2 + row)) * 512 + c4 * 4] = vv;
    }
    __syncthreads();
  }
}

// ---------------------------------------------------------------------------
// Workspace layout (bytes):
//   [0, 50331648)            proj f16  [49152][512]   (q rows 0.., k 16384.., v 32768..)
//   [50331648, 67108864)     xvT  f16  [8][512][2048]
//   [67108864, 67305472)     f    f32  [49152]
//   [67305472, 67502080)     c0   f32  [49152]
// ---------------------------------------------------------------------------
extern "C" void kernel_launch(void* const* d_in, const int* in_sizes, int n_in,
                              void* d_out, int out_size, void* d_ws, size_t ws_size,
                              hipStream_t stream) {
  (void)in_sizes; (void)n_in; (void)out_size; (void)ws_size;
  const float* xq = (const float*)d_in[0];
  const float* xk = (const float*)d_in[1];
  const float* xv = (const float*)d_in[2];
  const float* wq = (const float*)d_in[3];
  const float* bq = (const float*)d_in[4];
  const float* wk = (const float*)d_in[5];
  const float* bk = (const float*)d_in[6];
  const float* wv = (const float*)d_in[7];
  const float* bv = (const float*)d_in[8];
  float* out = (float*)d_out;
  char* ws = (char*)d_ws;

  _Float16* proj = (_Float16*)(ws);
  _Float16* xvT  = (_Float16*)(ws + 50331648);
  float* fsc     = (float*)(ws + 67108864);
  float* c0a     = (float*)(ws + 67305472);

  k_proj<<<dim3(4, 384), 256, 0, stream>>>(xq, xk, xv, wq, wk, wv, bq, bk, bv, proj);
  k_rowstats<<<dim3(12288), 256, 0, stream>>>(proj, fsc, c0a);
  k_transpose_v<<<dim3(32, 8, 8), 256, 0, stream>>>(proj, xvT);
  k_attn<<<dim3(64, 8), 256, 0, stream>>>(proj, xvT, fsc, c0a, out);
}

// Round 3
// 460.443 us; speedup vs baseline: 1.0462x; 1.0103x over previous
//
#include <hip/hip_runtime.h>
#include <hip/hip_bf16.h>
#include <cstdint>
#include <cstddef>

// ---------------------------------------------------------------------------
// EinsteinCore: hyperbolic attention, MI355X fp16-MFMA implementation.
// B=8, S=M=2048, K_in=1024, DH=DOUT=512, k=1 (sk=1), beta=1/sqrt(512).
//
// Math identities used (k=1):
//   Q0=cosh(th), Qs=f*x with f=sinh(th)*s/vn, s=min(3.5/(n+1e-7),1), th=vn=max(n*s,eps)
//   gamma*v_klein = Vs, gamma = V0  => mid = (sum p*Vs)/(sum p*V0), p unnormalized
//   p = (x+sqrt(x^2-1))^(-beta),  x = Q0*K0 - f_q*f_k*(xq . xk)  in [1, ~548]
//   out = d0 * mid/||mid||  (clip scale cancels), d0 = arccosh(max(z0,1+1e-7))
// ---------------------------------------------------------------------------

typedef _Float16 f16x8 __attribute__((ext_vector_type(8)));
typedef _Float16 f16x4 __attribute__((ext_vector_type(4)));
typedef float    f32x4 __attribute__((ext_vector_type(4)));

#define BETA_F 0.04419417382415922f
#define LOG2E_F 1.4426950408889634f
#define LN2_F 0.6931471805599453f

__device__ __forceinline__ void gload_lds16(const void* g, void* l) {
  __builtin_amdgcn_global_load_lds(
      (__attribute__((address_space(1))) void*)(g),
      (__attribute__((address_space(3))) void*)(l), 16, 0, 0);
}

// ---------------------------------------------------------------------------
// K1: fused projection GEMM.  proj[r][d] = sum_k X[r][k]*W[d][k] + b[d]
// r in [0,49152): rows 0..16383 = queries, 16384.. = keys, 32768.. = values.
// 128x128 tile, BK=32, 256 threads (4 waves, 64x64 quadrant per wave).
// Double-buffered LDS; global loads for tile t+1 issued right after the
// barrier so their latency hides under tile t's MFMA phase (1 barrier/step).
// 1-D grid, XCD-swizzled (1536 = 8 XCDs x 192) so the 4 column-tiles sharing
// one 512KB X row-slab run on the SAME XCD -> X fetched from HBM once.
// ---------------------------------------------------------------------------
#define K1_PIT 40   // f16 LDS pitch (80B: 16B-aligned frags, 2-way banks = free)

__global__ __launch_bounds__(256) void k_proj(
    const float* __restrict__ xq, const float* __restrict__ xk, const float* __restrict__ xv,
    const float* __restrict__ wq, const float* __restrict__ wk, const float* __restrict__ wv,
    const float* __restrict__ bq, const float* __restrict__ bk, const float* __restrict__ bv,
    _Float16* __restrict__ proj)
{
  __shared__ __align__(16) _Float16 As[2][128 * K1_PIT];   // 2 x 10 KB
  __shared__ __align__(16) _Float16 Bs[2][128 * K1_PIT];   // 2 x 10 KB

  const int tid = threadIdx.x;
  const int w = tid >> 6, l = tid & 63, ln = l & 15, q = l >> 4;
  const int wm = w & 1, wn = w >> 1;

  // XCD-aware swizzle: id -> (xcd, j); XCD x owns row-blocks [48x, 48x+48),
  // and the 4 column-tiles of each row-block are consecutive j on that XCD.
  const int id = blockIdx.x;              // 0..1535
  const int xcd = id & 7, j = id >> 3;    // j in [0,192)
  const int rowblk = xcd * 48 + (j >> 2); // 0..383
  const int colblk = j & 3;               // 0..3
  const int r0 = rowblk * 128;            // global output row base (0..49151)
  const int n0 = colblk * 128;            // output col base (0..511)
  const int which = r0 >> 14;             // 0=q,1=k,2=v (blocks never straddle)
  const int rloc = r0 & 16383;
  const float* X = (which == 0) ? xq : ((which == 1) ? xk : xv);
  const float* W = (which == 0) ? wq : ((which == 1) ? wk : wv);
  const float* bias = (which == 0) ? bq : ((which == 1) ? bk : bv);

  // per-thread staging coords: row = lrow + 32*it, 8 float4 per 32-wide row
  const int lrow = tid >> 3, lc4 = tid & 7;
  const float* Xb = X + (size_t)(rloc + lrow) * 1024 + lc4 * 4;
  const float* Wb = W + (size_t)(n0 + lrow) * 1024 + lc4 * 4;

  f32x4 acc[4][4];
#pragma unroll
  for (int mt = 0; mt < 4; ++mt)
#pragma unroll
    for (int nt = 0; nt < 4; ++nt) acc[mt][nt] = f32x4{0.f, 0.f, 0.f, 0.f};

  float4 ar[4], br[4];
#define K1_LOAD(kk)                                                      \
  {                                                                      \
    _Pragma("unroll") for (int it = 0; it < 4; ++it) {                   \
      ar[it] = *(const float4*)(Xb + (size_t)(32 * it) * 1024 + (kk));   \
      br[it] = *(const float4*)(Wb + (size_t)(32 * it) * 1024 + (kk));   \
    }                                                                    \
  }
#define K1_STORE(buf)                                                    \
  {                                                                      \
    _Pragma("unroll") for (int it = 0; it < 4; ++it) {                   \
      int row = lrow + 32 * it;                                          \
      f16x4 ah = { (_Float16)ar[it].x, (_Float16)ar[it].y,               \
                   (_Float16)ar[it].z, (_Float16)ar[it].w };             \
      f16x4 bh = { (_Float16)br[it].x, (_Float16)br[it].y,               \
                   (_Float16)br[it].z, (_Float16)br[it].w };             \
      *(f16x4*)&As[buf][row * K1_PIT + lc4 * 4] = ah;                    \
      *(f16x4*)&Bs[buf][row * K1_PIT + lc4 * 4] = bh;                    \
    }                                                                    \
  }

  // prologue: stage K-step 0 (latency exposed once)
  K1_LOAD(0);
  K1_STORE(0);
  int cur = 0;

  for (int kk = 0; kk < 1024; kk += 32) {
    __syncthreads();                       // LDS[cur] = tile t visible
    if (kk + 32 < 1024) K1_LOAD(kk + 32);  // issue t+1 loads; drain after MFMA

    f16x8 af[4], bf[4];
#pragma unroll
    for (int mt = 0; mt < 4; ++mt)
      af[mt] = *(const f16x8*)&As[cur][(wm * 64 + mt * 16 + ln) * K1_PIT + q * 8];
#pragma unroll
    for (int nt = 0; nt < 4; ++nt)
      bf[nt] = *(const f16x8*)&Bs[cur][(wn * 64 + nt * 16 + ln) * K1_PIT + q * 8];
#pragma unroll
    for (int mt = 0; mt < 4; ++mt)
#pragma unroll
      for (int nt = 0; nt < 4; ++nt)
        acc[mt][nt] = __builtin_amdgcn_mfma_f32_16x16x32_f16(af[mt], bf[nt], acc[mt][nt], 0, 0, 0);

    if (kk + 32 < 1024) K1_STORE(cur ^ 1); // vmcnt wait lands here, under MFMA
    cur ^= 1;
  }
#undef K1_LOAD
#undef K1_STORE

  float bl[4];
#pragma unroll
  for (int nt = 0; nt < 4; ++nt) bl[nt] = bias[n0 + wn * 64 + nt * 16 + ln];
#pragma unroll
  for (int mt = 0; mt < 4; ++mt)
#pragma unroll
    for (int nt = 0; nt < 4; ++nt)
#pragma unroll
      for (int i = 0; i < 4; ++i) {
        int r = r0 + wm * 64 + mt * 16 + q * 4 + i;
        int c = n0 + wn * 64 + nt * 16 + ln;
        proj[(size_t)r * 512 + c] = (_Float16)(acc[mt][nt][i] + bl[nt]);
      }
}

// ---------------------------------------------------------------------------
// K2a: per-row expmap scalars.  f[r] = sinh(th)*s/vn,  c0[r] = cosh(th).
// One wave per row (512 elems = 8/lane).
// ---------------------------------------------------------------------------
__global__ __launch_bounds__(256) void k_rowstats(
    const _Float16* __restrict__ proj, float* __restrict__ fs, float* __restrict__ c0)
{
  const int w = threadIdx.x >> 6, l = threadIdx.x & 63;
  const int r = blockIdx.x * 4 + w;
  const f16x8 v = *(const f16x8*)(proj + (size_t)r * 512 + l * 8);
  float ss = 0.f;
#pragma unroll
  for (int j = 0; j < 8; ++j) { float x = (float)v[j]; ss += x * x; }
#pragma unroll
  for (int m = 1; m < 64; m <<= 1) ss += __shfl_xor(ss, m, 64);
  if (l == 0) {
    float n = sqrtf(ss);
    float s = fminf(3.5f / (n + 1e-7f), 1.0f);
    float vn = fmaxf(n * s, 1e-12f);
    float e = __builtin_amdgcn_exp2f(vn * LOG2E_F);
    float ie = 1.0f / e;
    c0[r] = 0.5f * (e + ie);
    fs[r] = 0.5f * (e - ie) * s / vn;
  }
}

// ---------------------------------------------------------------------------
// K2b: transpose V-projection to xvT[b][d][m] (m-contiguous for PV B-frags).
// 64x64 tiles through LDS.
// ---------------------------------------------------------------------------
#define K2_TP 72   // ushort pitch (144B rows)

__global__ __launch_bounds__(256) void k_transpose_v(
    const _Float16* __restrict__ proj, _Float16* __restrict__ xvT)
{
  __shared__ __align__(16) unsigned short t[64 * K2_TP];
  const int b = blockIdx.z, m0 = blockIdx.x * 64, d0 = blockIdx.y * 64;
  const unsigned short* pv =
      (const unsigned short*)(proj + (size_t)(32768 + b * 2048 + m0) * 512);
#pragma unroll
  for (int it = 0; it < 2; ++it) {
    int v = threadIdx.x + 256 * it;
    int r = v >> 3, c4 = v & 7;
    uint4 dd = *(const uint4*)(pv + (size_t)r * 512 + d0 + c4 * 8);
    *(uint4*)&t[r * K2_TP + c4 * 8] = dd;
  }
  __syncthreads();
#pragma unroll
  for (int it = 0; it < 2; ++it) {
    int v = threadIdx.x + 256 * it;
    int dr = v >> 3, mc = v & 7;
    unsigned int o[4];
#pragma unroll
    for (int jj = 0; jj < 4; ++jj) {
      unsigned int lo = t[(mc * 8 + jj * 2) * K2_TP + dr];
      unsigned int hi = t[(mc * 8 + jj * 2 + 1) * K2_TP + dr];
      o[jj] = lo | (hi << 16);
    }
    uint4 dd = { o[0], o[1], o[2], o[3] };
    unsigned short* dst =
        (unsigned short*)(xvT + ((size_t)b * 512 + d0 + dr) * 2048 + m0 + mc * 8);
    *(uint4*)dst = dd;
  }
}

// ---------------------------------------------------------------------------
// K3: fused hyperbolic attention — double-buffered pipelined schedule.
// Block = (b, 32 s-rows), 256 threads (4 waves).  m-tiles of 32.
// Wave roles QK: rh=w>>1 (s half), ch=w&1 (m half).  PV: wave owns d-chunk w*128.
// K-tiles live in KA (32KB), V-tiles in KB (32KB).  2 barriers per tile:
//   sync#1: KA=K[t] visible / PV[t-1] done with KB,P
//     issue V[t]->KB ; QK on KA ; epilogue -> P        (V latency under QK)
//   sync#2: KB=V[t] visible / KA reads + P writes done
//     issue K[t+1]->KA ; PV on KB                      (K latency under PV)
// No barrier ever drains a load issued in the same phase.
// global_load_lds(16B) with XOR-swizzled gptrs for conflict-free ds_read_b128.
// ---------------------------------------------------------------------------
__global__ __launch_bounds__(256, 2) void k_attn(
    const _Float16* __restrict__ proj, const _Float16* __restrict__ xvT,
    const float* __restrict__ fs, const float* __restrict__ c0,
    float* __restrict__ out)
{
  __shared__ __align__(16) _Float16 KA[16384];     // 32 KB: K tile [32 m][512 k]
  __shared__ __align__(16) _Float16 KB[16384];     // 32 KB: V tile [512 d][32 m]
  __shared__ __align__(16) _Float16 P[32 * 40];    // p*f_v tile, pitch 40 (80B)
  __shared__ float s_den[2][32];
  __shared__ float s_mn2[4][32];
  __shared__ float s_g[32];

  const int tid = threadIdx.x;
  const int w = tid >> 6, l = tid & 63, ln = l & 15, q = l >> 4;
  const int rh = w >> 1, ch = w & 1;
  const int b = blockIdx.y;
  const int s0 = blockIdx.x * 32;

  const _Float16* projq = proj + (size_t)(b * 2048 + s0) * 512;
  const _Float16* projk = proj + (size_t)(16384 + b * 2048) * 512;
  const _Float16* vt = xvT + (size_t)b * 512 * 2048;
  const float* fqp = fs + b * 2048 + s0;
  const float* fkp = fs + 16384 + b * 2048;
  const float* fvp = fs + 32768 + b * 2048;
  const float* cqp = c0 + b * 2048 + s0;
  const float* ckp = c0 + 16384 + b * 2048;
  const float* cvp = c0 + 32768 + b * 2048;

  // --- prologue: stage K[0] into KA first so its latency overlaps Q loads ---
#pragma unroll
  for (int rr = 0; rr < 8; ++rr) {
    int mloc = w * 8 + rr;
    const _Float16* g = projk + (size_t)mloc * 512 + ((l ^ (mloc & 7)) * 8);
    gload_lds16(g, &KA[mloc * 512]);
  }

  // Q fragments resident in registers: rows rh*16+ln, all 512 k.
  f16x8 qf[16];
  {
    const _Float16* qrow = projq + (size_t)(rh * 16 + ln) * 512;
#pragma unroll
    for (int kc = 0; kc < 16; ++kc) qf[kc] = *(const f16x8*)(qrow + kc * 32 + q * 8);
  }
  float cq_i[4], fq_i[4];
#pragma unroll
  for (int i = 0; i < 4; ++i) {
    cq_i[i] = cqp[rh * 16 + q * 4 + i];
    fq_i[i] = fqp[rh * 16 + q * 4 + i];
  }
  // tile-0 per-lane K/V row scalars
  const int mll = ch * 16 + ln;
  float ck_c = ckp[mll], fk_c = fkp[mll], fv_c = fvp[mll], cv_c = cvp[mll];

  f32x4 acc[2][8];
#pragma unroll
  for (int rt = 0; rt < 2; ++rt)
#pragma unroll
    for (int nt = 0; nt < 8; ++nt) acc[rt][nt] = f32x4{0.f, 0.f, 0.f, 0.f};
  float den_acc[4] = {0.f, 0.f, 0.f, 0.f};

  for (int m0 = 0; m0 < 2048; m0 += 32) {
    __syncthreads();                             // KA=K[t] visible; PV[t-1] done w/ KB,P
    // --- issue V[t] stage into KB: [d 0..511][m 0..31], 16 d-rows/instr ---
#pragma unroll
    for (int uu = 0; uu < 8; ++uu) {
      int u = w * 8 + uu;
      int dloc = u * 16 + (l >> 2);
      int cg = (l & 3) ^ ((dloc >> 1) & 3);
      const _Float16* g = vt + (size_t)dloc * 2048 + m0 + cg * 8;
      gload_lds16(g, &KB[u * 512]);
    }
    // --- prefetch next-tile per-lane scalars (drain at sync#2, under QK) ---
    float ck_n = 0.f, fk_n = 0.f, fv_n = 0.f, cv_n = 0.f;
    if (m0 + 32 < 2048) {
      int mn = m0 + 32 + ch * 16 + ln;
      ck_n = ckp[mn]; fk_n = fkp[mn]; fv_n = fvp[mn]; cv_n = cvp[mn];
    }

    // --- QK: P-quarter (rh, ch), K=512, on KA ---
    f32x4 pacc = f32x4{0.f, 0.f, 0.f, 0.f};
    {
      const _Float16* krow = &KA[(ch * 16 + ln) * 512];
      const int msw = (ch * 16 + ln) & 7;
#pragma unroll
      for (int kc = 0; kc < 16; ++kc) {
        f16x8 kf = *(const f16x8*)(krow + (((kc * 4 + q) ^ msw) * 8));
        pacc = __builtin_amdgcn_mfma_f32_16x16x32_f16(qf[kc], kf, pacc, 0, 0, 0);
      }
    }
    // --- score epilogue: p = (x+sqrt(x^2-1))^(-beta) ---
#pragma unroll
    for (int i = 0; i < 4; ++i) {
      float x = cq_i[i] * ck_c - (fq_i[i] * fk_c) * pacc[i];
      x = fmaxf(x, 1.0f + 1e-7f);
      float r_ = x + __builtin_amdgcn_sqrtf(x * x - 1.0f);
      float p = __builtin_amdgcn_exp2f(-BETA_F * __builtin_amdgcn_logf(r_));
      den_acc[i] += p * cv_c;
      P[(rh * 16 + q * 4 + i) * 40 + ch * 16 + ln] = (_Float16)(p * fv_c);
    }
    __syncthreads();                             // KB=V[t] visible; KA dead; P visible
    // --- issue K[t+1] stage into KA (drains at next sync#1, under PV) ---
    if (m0 + 32 < 2048) {
#pragma unroll
      for (int rr = 0; rr < 8; ++rr) {
        int mloc = w * 8 + rr;
        const _Float16* g = projk + (size_t)(m0 + 32 + mloc) * 512 + ((l ^ (mloc & 7)) * 8);
        gload_lds16(g, &KA[mloc * 512]);
      }
    }
    // --- PV: num[s][d] += P[s][m] * xv[m][d], on KB ---
#pragma unroll
    for (int rt = 0; rt < 2; ++rt) {
      f16x8 pf = *(const f16x8*)&P[(rt * 16 + ln) * 40 + q * 8];
#pragma unroll
      for (int nt = 0; nt < 8; ++nt) {
        int d = w * 128 + nt * 16 + ln;
        f16x8 vf = *(const f16x8*)&KB[d * 32 + ((q ^ ((d >> 1) & 3)) * 8)];
        acc[rt][nt] = __builtin_amdgcn_mfma_f32_16x16x32_f16(pf, vf, acc[rt][nt], 0, 0, 0);
      }
    }
    ck_c = ck_n; fk_c = fk_n; fv_c = fv_n; cv_c = cv_n;
  }

  // ---- den reduction: sum over the 16 m-lanes, then over ch halves ----
#pragma unroll
  for (int i = 0; i < 4; ++i) {
    float v = den_acc[i];
    v += __shfl_xor(v, 1, 64); v += __shfl_xor(v, 2, 64);
    v += __shfl_xor(v, 4, 64); v += __shfl_xor(v, 8, 64);
    if (ln == 0) s_den[ch][rh * 16 + q * 4 + i] = v;
  }
  __syncthreads();
  if (tid < 32) {
    float dv = fmaxf(s_den[0][tid] + s_den[1][tid], 1e-12f);
    s_den[0][tid] = 1.0f / dv;                   // invden
  }
  __syncthreads();
  // ---- ||mid||^2 partials ----
#pragma unroll
  for (int rt = 0; rt < 2; ++rt)
#pragma unroll
    for (int i = 0; i < 4; ++i) {
      int s = rt * 16 + q * 4 + i;
      float inv = s_den[0][s];
      float mm = 0.f;
#pragma unroll
      for (int nt = 0; nt < 8; ++nt) {
        float mid = acc[rt][nt][i] * inv;
        mm += mid * mid;
      }
      mm += __shfl_xor(mm, 1, 64); mm += __shfl_xor(mm, 2, 64);
      mm += __shfl_xor(mm, 4, 64); mm += __shfl_xor(mm, 8, 64);
      if (ln == 0) s_mn2[w][s] = mm;
    }
  __syncthreads();
  if (tid < 32) {
    float mn2 = s_mn2[0][tid] + s_mn2[1][tid] + s_mn2[2][tid] + s_mn2[3][tid];
    float mn = sqrtf(mn2);
    float sc = (mn >= 1.0f) ? (1.0f - 1e-6f) / mn : 1.0f;
    float mn2c = fminf(mn2 * sc * sc, 1.0f - 1e-6f);
    float z0 = 1.0f / sqrtf(fmaxf(1.0f - mn2c, 1e-12f));
    float zc = fmaxf(z0, 1.0f + 1e-7f);
    float d0 = LN2_F * __builtin_amdgcn_logf(zc + __builtin_amdgcn_sqrtf(zc * zc - 1.0f));
    s_g[tid] = (d0 / fmaxf(mn, 1e-12f)) * s_den[0][tid];   // out = s_g[s] * num
  }
  __syncthreads();

  // ---- transpose 2 s-rows at a time through LDS, coalesced float4 stores ----
  float* pbuf = (float*)KA;                      // 4KB of the dead K buffer
  for (int sp = 0; sp < 16; ++sp) {
#pragma unroll
    for (int rt = 0; rt < 2; ++rt)
#pragma unroll
      for (int i = 0; i < 4; ++i) {
        int s = rt * 16 + q * 4 + i;
        if ((s >> 1) == sp) {
          float gg = s_g[s];
#pragma unroll
          for (int nt = 0; nt < 8; ++nt)
            pbuf[(s & 1) * 512 + w * 128 + nt * 16 + ln] = gg * acc[rt][nt][i];
        }
      }
    __syncthreads();
    {
      int row = tid >> 7, c4 = tid & 127;
      float4 vv = *(float4*)&pbuf[row * 512 + c4 * 4];
      *(float4*)&out[((size_t)(b * 2048 + s0 + sp * 2 + row)) * 512 + c4 * 4] = vv;
    }
    __syncthreads();
  }
}

// ---------------------------------------------------------------------------
// Workspace layout (bytes):
//   [0, 50331648)            proj f16  [49152][512]   (q rows 0.., k 16384.., v 32768..)
//   [50331648, 67108864)     xvT  f16  [8][512][2048]
//   [67108864, 67305472)     f    f32  [49152]
//   [67305472, 67502080)     c0   f32  [49152]
// ---------------------------------------------------------------------------
extern "C" void kernel_launch(void* const* d_in, const int* in_sizes, int n_in,
                              void* d_out, int out_size, void* d_ws, size_t ws_size,
                              hipStream_t stream) {
  (void)in_sizes; (void)n_in; (void)out_size; (void)ws_size;
  const float* xq = (const float*)d_in[0];
  const float* xk = (const float*)d_in[1];
  const float* xv = (const float*)d_in[2];
  const float* wq = (const float*)d_in[3];
  const float* bq = (const float*)d_in[4];
  const float* wk = (const float*)d_in[5];
  const float* bk = (const float*)d_in[6];
  const float* wv = (const float*)d_in[7];
  const float* bv = (const float*)d_in[8];
  float* out = (float*)d_out;
  char* ws = (char*)d_ws;

  _Float16* proj = (_Float16*)(ws);
  _Float16* xvT  = (_Float16*)(ws + 50331648);
  float* fsc     = (float*)(ws + 67108864);
  float* c0a     = (float*)(ws + 67305472);

  k_proj<<<dim3(1536), 256, 0, stream>>>(xq, xk, xv, wq, wk, wv, bq, bk, bv, proj);
  k_rowstats<<<dim3(12288), 256, 0, stream>>>(proj, fsc, c0a);
  k_transpose_v<<<dim3(32, 8, 8), 256, 0, stream>>>(proj, xvT);
  k_attn<<<dim3(64, 8), 256, 0, stream>>>(proj, xvT, fsc, c0a, out);
}

// Round 6
// 448.603 us; speedup vs baseline: 1.0738x; 1.0264x over previous
//
#include <hip/hip_runtime.h>
#include <hip/hip_bf16.h>
#include <cstdint>
#include <cstddef>

// ---------------------------------------------------------------------------
// EinsteinCore: hyperbolic attention, MI355X fp16-MFMA implementation.
// B=8, S=M=2048, K_in=1024, DH=DOUT=512, k=1 (sk=1), beta=1/sqrt(512).
//
// Math identities used (k=1):
//   Q0=cosh(th), Qs=f*x with f=sinh(th)*s/vn, s=min(3.5/(n+1e-7),1), th=vn=max(n*s,eps)
//   gamma*v_klein = Vs, gamma = V0  => mid = (sum p*Vs)/(sum p*V0), p unnormalized
//   p = (x+sqrt(x^2-1))^(-beta),  x = Q0*K0 - f_q*f_k*(xq . xk)  in [1, ~548]
//   out = d0 * mid/||mid||  (clip scale cancels), d0 = arccosh(max(z0,1+1e-7))
//
// Memory plan — STRICTLY inside the proven 67,502,080-byte workspace:
//   ws[0, 50331648)          proj f16 [49152][512]
//   ws[50331648, 67108864)   xvT region; its FIRST 3,145,728 B host wh
//                            (wh dead before k_transpose_v overwrites it)
//   ws[67108864, 67502080)   f / c0 scalars
//   d_out (33,554,432 B)     xs: one 16384-row f16 X part (dead till k_attn)
// Sequence: cvt_w -> (cvt_x[p] -> proj[p]) x3 -> rowstats -> transpose_v -> attn.
// ---------------------------------------------------------------------------

typedef _Float16 f16x8 __attribute__((ext_vector_type(8)));
typedef _Float16 f16x4 __attribute__((ext_vector_type(4)));
typedef float    f32x4 __attribute__((ext_vector_type(4)));

#define BETA_F 0.04419417382415922f
#define LOG2E_F 1.4426950408889634f
#define LN2_F 0.6931471805599453f

__device__ __forceinline__ void gload_lds16(const void* g, void* l) {
  __builtin_amdgcn_global_load_lds(
      (__attribute__((address_space(1))) void*)(g),
      (__attribute__((address_space(3))) void*)(l), 16, 0, 0);
}

// ---------------------------------------------------------------------------
// K0a: W fp32 -> f16.  wh[1536][1024]: rows 0..511=wq, 512..=wk, 1024..=wv.
// 196608 chunks of 8 elems; 768 blocks.
// ---------------------------------------------------------------------------
__global__ __launch_bounds__(256) void k_cvt_w(
    const float* __restrict__ wq, const float* __restrict__ wk,
    const float* __restrict__ wv, _Float16* __restrict__ wh)
{
  size_t cid = (size_t)blockIdx.x * 256 + threadIdx.x;   // 0..196607
  int m = (int)(cid >> 16);
  size_t off = (cid & 65535) << 3;
  const float* src = (m == 0 ? wq : (m == 1 ? wk : wv)) + off;
  float4 a = *(const float4*)src;
  float4 b = *(const float4*)(src + 4);
  f16x8 h = { (_Float16)a.x, (_Float16)a.y, (_Float16)a.z, (_Float16)a.w,
              (_Float16)b.x, (_Float16)b.y, (_Float16)b.z, (_Float16)b.w };
  *(f16x8*)(wh + (cid << 3)) = h;
}

// ---------------------------------------------------------------------------
// K0b: one X part (16384 rows x 1024) fp32 -> f16 into scratch (d_out).
// 2097152 chunks of 8 elems; 8192 blocks.
// ---------------------------------------------------------------------------
__global__ __launch_bounds__(256) void k_cvt_x(
    const float* __restrict__ src, _Float16* __restrict__ dst)
{
  size_t cid = (size_t)blockIdx.x * 256 + threadIdx.x;   // 0..2097151
  const float* s = src + (cid << 3);
  float4 a = *(const float4*)s;
  float4 b = *(const float4*)(s + 4);
  f16x8 h = { (_Float16)a.x, (_Float16)a.y, (_Float16)a.z, (_Float16)a.w,
              (_Float16)b.x, (_Float16)b.y, (_Float16)b.z, (_Float16)b.w };
  *(f16x8*)(dst + (cid << 3)) = h;
}

// ---------------------------------------------------------------------------
// K1: projection GEMM for ONE part, pure f16 + global_load_lds DMA.
// proj[r][d] = sum_k xh[r][k]*wh[d][k] + bias[d],  r in [0,16384) local.
// 128x128 tile, BK=32, 256 threads (4 waves, 64x64 quadrant per wave).
// Double-buffered 32KB LDS, 1 barrier/step; barrier's vmcnt(0) drains the
// DMA issued one full MFMA phase earlier.  Staging: 4 gload_lds16/thread,
// linear LDS dest (wave-uniform base + lane*16), XOR-swizzled GLOBAL source
// chunk (ss ^ (row&3)); frag ds_read_b128 applies the same XOR -> 2-way bank
// aliasing only (free).  XCD-swizzled 1-D grid: 512 = 8 XCDs x 64, the 4
// column-tiles of each 128-row slab run consecutively on the SAME XCD.
// ---------------------------------------------------------------------------
__global__ __launch_bounds__(256, 4) void k_proj(
    const _Float16* __restrict__ xh, const _Float16* __restrict__ wh,
    const float* __restrict__ bias, _Float16* __restrict__ proj)
{
  __shared__ __align__(16) _Float16 Ab[2][128 * 32];   // 2 x 8 KB
  __shared__ __align__(16) _Float16 Bb[2][128 * 32];   // 2 x 8 KB

  const int tid = threadIdx.x;
  const int w = tid >> 6, l = tid & 63, ln = l & 15, q = l >> 4;
  const int wm = w & 1, wn = w >> 1;

  const int id = blockIdx.x;              // 0..511
  const int xcd = id & 7, j = id >> 3;    // j in [0,64)
  const int rowblk = xcd * 16 + (j >> 2); // 0..127
  const int colblk = j & 3;               // 0..3
  const int r0 = rowblk * 128;            // local output row base (0..16383)
  const int n0 = colblk * 128;            // output col base (0..511)
  const _Float16* Xrow = xh + (size_t)r0 * 1024;
  const _Float16* Wrow = wh + (size_t)n0 * 1024;

  const int srr = l >> 2, ss = l & 3;     // staging: row-in-region, 16B slot

  f32x4 acc[4][4];
#pragma unroll
  for (int mt = 0; mt < 4; ++mt)
#pragma unroll
    for (int nt = 0; nt < 4; ++nt) acc[mt][nt] = f32x4{0.f, 0.f, 0.f, 0.f};

  // Each wave stages 2 regions of 1KB for A and B (regions i*4+w, i=0,1);
  // region base is wave-uniform, HW adds lane*16B.  Global chunk index is
  // pre-swizzled: slot ss sources chunk (ss ^ (row&3)).
#define K1_STAGE(buf, kk)                                                    \
  {                                                                          \
    _Pragma("unroll") for (int i = 0; i < 2; ++i) {                          \
      int ar = (i * 4 + w) * 16 + srr;                                       \
      gload_lds16(Xrow + (size_t)ar * 1024 + (kk) + ((ss ^ (ar & 3)) << 3),  \
                  &Ab[buf][(i * 4 + w) * 512]);                              \
      gload_lds16(Wrow + (size_t)ar * 1024 + (kk) + ((ss ^ (ar & 3)) << 3),  \
                  &Bb[buf][(i * 4 + w) * 512]);                              \
    }                                                                        \
  }

  K1_STAGE(0, 0);                          // prologue (latency exposed once)
  int cur = 0;

  for (int kk = 0; kk < 1024; kk += 32) {
    __syncthreads();                       // vmcnt(0): buf[cur] DMA complete
    if (kk + 32 < 1024) K1_STAGE(cur ^ 1, kk + 32);  // in flight across MFMA

    f16x8 af[4], bf[4];
#pragma unroll
    for (int mt = 0; mt < 4; ++mt) {
      int ar = wm * 64 + mt * 16 + ln;
      af[mt] = *(const f16x8*)&Ab[cur][ar * 32 + ((q ^ (ar & 3)) << 3)];
    }
#pragma unroll
    for (int nt = 0; nt < 4; ++nt) {
      int br = wn * 64 + nt * 16 + ln;
      bf[nt] = *(const f16x8*)&Bb[cur][br * 32 + ((q ^ (br & 3)) << 3)];
    }
#pragma unroll
    for (int mt = 0; mt < 4; ++mt)
#pragma unroll
      for (int nt = 0; nt < 4; ++nt)
        acc[mt][nt] = __builtin_amdgcn_mfma_f32_16x16x32_f16(af[mt], bf[nt], acc[mt][nt], 0, 0, 0);
    cur ^= 1;
  }
#undef K1_STAGE

  float bl[4];
#pragma unroll
  for (int nt = 0; nt < 4; ++nt) bl[nt] = bias[n0 + wn * 64 + nt * 16 + ln];
#pragma unroll
  for (int mt = 0; mt < 4; ++mt)
#pragma unroll
    for (int nt = 0; nt < 4; ++nt)
#pragma unroll
      for (int i = 0; i < 4; ++i) {
        int r = r0 + wm * 64 + mt * 16 + q * 4 + i;
        int c = n0 + wn * 64 + nt * 16 + ln;
        proj[(size_t)r * 512 + c] = (_Float16)(acc[mt][nt][i] + bl[nt]);
      }
}

// ---------------------------------------------------------------------------
// K2a: per-row expmap scalars.  f[r] = sinh(th)*s/vn,  c0[r] = cosh(th).
// One wave per row (512 elems = 8/lane).
// ---------------------------------------------------------------------------
__global__ __launch_bounds__(256) void k_rowstats(
    const _Float16* __restrict__ proj, float* __restrict__ fs, float* __restrict__ c0)
{
  const int w = threadIdx.x >> 6, l = threadIdx.x & 63;
  const int r = blockIdx.x * 4 + w;
  const f16x8 v = *(const f16x8*)(proj + (size_t)r * 512 + l * 8);
  float ss = 0.f;
#pragma unroll
  for (int j = 0; j < 8; ++j) { float x = (float)v[j]; ss += x * x; }
#pragma unroll
  for (int m = 1; m < 64; m <<= 1) ss += __shfl_xor(ss, m, 64);
  if (l == 0) {
    float n = sqrtf(ss);
    float s = fminf(3.5f / (n + 1e-7f), 1.0f);
    float vn = fmaxf(n * s, 1e-12f);
    float e = __builtin_amdgcn_exp2f(vn * LOG2E_F);
    float ie = 1.0f / e;
    c0[r] = 0.5f * (e + ie);
    fs[r] = 0.5f * (e - ie) * s / vn;
  }
}

// ---------------------------------------------------------------------------
// K2b: transpose V-projection to xvT[b][d][m] (m-contiguous for PV B-frags).
// 64x64 tiles through LDS.  Runs AFTER all k_proj parts -> safely overwrites
// the wh staging bytes at the start of the xvT region.
// ---------------------------------------------------------------------------
#define K2_TP 72   // ushort pitch (144B rows)

__global__ __launch_bounds__(256) void k_transpose_v(
    const _Float16* __restrict__ proj, _Float16* __restrict__ xvT)
{
  __shared__ __align__(16) unsigned short t[64 * K2_TP];
  const int b = blockIdx.z, m0 = blockIdx.x * 64, d0 = blockIdx.y * 64;
  const unsigned short* pv =
      (const unsigned short*)(proj + (size_t)(32768 + b * 2048 + m0) * 512);
#pragma unroll
  for (int it = 0; it < 2; ++it) {
    int v = threadIdx.x + 256 * it;
    int r = v >> 3, c4 = v & 7;
    uint4 dd = *(const uint4*)(pv + (size_t)r * 512 + d0 + c4 * 8);
    *(uint4*)&t[r * K2_TP + c4 * 8] = dd;
  }
  __syncthreads();
#pragma unroll
  for (int it = 0; it < 2; ++it) {
    int v = threadIdx.x + 256 * it;
    int dr = v >> 3, mc = v & 7;
    unsigned int o[4];
#pragma unroll
    for (int jj = 0; jj < 4; ++jj) {
      unsigned int lo = t[(mc * 8 + jj * 2) * K2_TP + dr];
      unsigned int hi = t[(mc * 8 + jj * 2 + 1) * K2_TP + dr];
      o[jj] = lo | (hi << 16);
    }
    uint4 dd = { o[0], o[1], o[2], o[3] };
    unsigned short* dst =
        (unsigned short*)(xvT + ((size_t)b * 512 + d0 + dr) * 2048 + m0 + mc * 8);
    *(uint4*)dst = dd;
  }
}

// ---------------------------------------------------------------------------
// K3: fused hyperbolic attention — double-buffered pipelined schedule.
// Block = (b, 32 s-rows), 256 threads (4 waves).  m-tiles of 32.
// Wave roles QK: rh=w>>1 (s half), ch=w&1 (m half).  PV: wave owns d-chunk w*128.
// K-tiles live in KA (32KB), V-tiles in KB (32KB).  2 barriers per tile:
//   sync#1: KA=K[t] visible / PV[t-1] done with KB,P
//     issue V[t]->KB ; QK on KA ; epilogue -> P        (V latency under QK)
//   sync#2: KB=V[t] visible / KA reads + P writes done
//     issue K[t+1]->KA ; PV on KB                      (K latency under PV)
// No barrier ever drains a load issued in the same phase.
// global_load_lds(16B) with XOR-swizzled gptrs for conflict-free ds_read_b128.
// ---------------------------------------------------------------------------
__global__ __launch_bounds__(256, 2) void k_attn(
    const _Float16* __restrict__ proj, const _Float16* __restrict__ xvT,
    const float* __restrict__ fs, const float* __restrict__ c0,
    float* __restrict__ out)
{
  __shared__ __align__(16) _Float16 KA[16384];     // 32 KB: K tile [32 m][512 k]
  __shared__ __align__(16) _Float16 KB[16384];     // 32 KB: V tile [512 d][32 m]
  __shared__ __align__(16) _Float16 P[32 * 40];    // p*f_v tile, pitch 40 (80B)
  __shared__ float s_den[2][32];
  __shared__ float s_mn2[4][32];
  __shared__ float s_g[32];

  const int tid = threadIdx.x;
  const int w = tid >> 6, l = tid & 63, ln = l & 15, q = l >> 4;
  const int rh = w >> 1, ch = w & 1;
  const int b = blockIdx.y;
  const int s0 = blockIdx.x * 32;

  const _Float16* projq = proj + (size_t)(b * 2048 + s0) * 512;
  const _Float16* projk = proj + (size_t)(16384 + b * 2048) * 512;
  const _Float16* vt = xvT + (size_t)b * 512 * 2048;
  const float* fqp = fs + b * 2048 + s0;
  const float* fkp = fs + 16384 + b * 2048;
  const float* fvp = fs + 32768 + b * 2048;
  const float* cqp = c0 + b * 2048 + s0;
  const float* ckp = c0 + 16384 + b * 2048;
  const float* cvp = c0 + 32768 + b * 2048;

  // --- prologue: stage K[0] into KA first so its latency overlaps Q loads ---
#pragma unroll
  for (int rr = 0; rr < 8; ++rr) {
    int mloc = w * 8 + rr;
    const _Float16* g = projk + (size_t)mloc * 512 + ((l ^ (mloc & 7)) * 8);
    gload_lds16(g, &KA[mloc * 512]);
  }

  // Q fragments resident in registers: rows rh*16+ln, all 512 k.
  f16x8 qf[16];
  {
    const _Float16* qrow = projq + (size_t)(rh * 16 + ln) * 512;
#pragma unroll
    for (int kc = 0; kc < 16; ++kc) qf[kc] = *(const f16x8*)(qrow + kc * 32 + q * 8);
  }
  float cq_i[4], fq_i[4];
#pragma unroll
  for (int i = 0; i < 4; ++i) {
    cq_i[i] = cqp[rh * 16 + q * 4 + i];
    fq_i[i] = fqp[rh * 16 + q * 4 + i];
  }
  // tile-0 per-lane K/V row scalars
  const int mll = ch * 16 + ln;
  float ck_c = ckp[mll], fk_c = fkp[mll], fv_c = fvp[mll], cv_c = cvp[mll];

  f32x4 acc[2][8];
#pragma unroll
  for (int rt = 0; rt < 2; ++rt)
#pragma unroll
    for (int nt = 0; nt < 8; ++nt) acc[rt][nt] = f32x4{0.f, 0.f, 0.f, 0.f};
  float den_acc[4] = {0.f, 0.f, 0.f, 0.f};

  for (int m0 = 0; m0 < 2048; m0 += 32) {
    __syncthreads();                             // KA=K[t] visible; PV[t-1] done w/ KB,P
    // --- issue V[t] stage into KB: [d 0..511][m 0..31], 16 d-rows/instr ---
#pragma unroll
    for (int uu = 0; uu < 8; ++uu) {
      int u = w * 8 + uu;
      int dloc = u * 16 + (l >> 2);
      int cg = (l & 3) ^ ((dloc >> 1) & 3);
      const _Float16* g = vt + (size_t)dloc * 2048 + m0 + cg * 8;
      gload_lds16(g, &KB[u * 512]);
    }
    // --- prefetch next-tile per-lane scalars (drain at sync#2, under QK) ---
    float ck_n = 0.f, fk_n = 0.f, fv_n = 0.f, cv_n = 0.f;
    if (m0 + 32 < 2048) {
      int mn = m0 + 32 + ch * 16 + ln;
      ck_n = ckp[mn]; fk_n = fkp[mn]; fv_n = fvp[mn]; cv_n = cvp[mn];
    }

    // --- QK: P-quarter (rh, ch), K=512, on KA ---
    f32x4 pacc = f32x4{0.f, 0.f, 0.f, 0.f};
    {
      const _Float16* krow = &KA[(ch * 16 + ln) * 512];
      const int msw = (ch * 16 + ln) & 7;
#pragma unroll
      for (int kc = 0; kc < 16; ++kc) {
        f16x8 kf = *(const f16x8*)(krow + (((kc * 4 + q) ^ msw) * 8));
        pacc = __builtin_amdgcn_mfma_f32_16x16x32_f16(qf[kc], kf, pacc, 0, 0, 0);
      }
    }
    // --- score epilogue: p = (x+sqrt(x^2-1))^(-beta) ---
#pragma unroll
    for (int i = 0; i < 4; ++i) {
      float x = cq_i[i] * ck_c - (fq_i[i] * fk_c) * pacc[i];
      x = fmaxf(x, 1.0f + 1e-7f);
      float r_ = x + __builtin_amdgcn_sqrtf(x * x - 1.0f);
      float p = __builtin_amdgcn_exp2f(-BETA_F * __builtin_amdgcn_logf(r_));
      den_acc[i] += p * cv_c;
      P[(rh * 16 + q * 4 + i) * 40 + ch * 16 + ln] = (_Float16)(p * fv_c);
    }
    __syncthreads();                             // KB=V[t] visible; KA dead; P visible
    // --- issue K[t+1] stage into KA (drains at next sync#1, under PV) ---
    if (m0 + 32 < 2048) {
#pragma unroll
      for (int rr = 0; rr < 8; ++rr) {
        int mloc = w * 8 + rr;
        const _Float16* g = projk + (size_t)(m0 + 32 + mloc) * 512 + ((l ^ (mloc & 7)) * 8);
        gload_lds16(g, &KA[mloc * 512]);
      }
    }
    // --- PV: num[s][d] += P[s][m] * xv[m][d], on KB ---
#pragma unroll
    for (int rt = 0; rt < 2; ++rt) {
      f16x8 pf = *(const f16x8*)&P[(rt * 16 + ln) * 40 + q * 8];
#pragma unroll
      for (int nt = 0; nt < 8; ++nt) {
        int d = w * 128 + nt * 16 + ln;
        f16x8 vf = *(const f16x8*)&KB[d * 32 + ((q ^ ((d >> 1) & 3)) * 8)];
        acc[rt][nt] = __builtin_amdgcn_mfma_f32_16x16x32_f16(pf, vf, acc[rt][nt], 0, 0, 0);
      }
    }
    ck_c = ck_n; fk_c = fk_n; fv_c = fv_n; cv_c = cv_n;
  }

  // ---- den reduction: sum over the 16 m-lanes, then over ch halves ----
#pragma unroll
  for (int i = 0; i < 4; ++i) {
    float v = den_acc[i];
    v += __shfl_xor(v, 1, 64); v += __shfl_xor(v, 2, 64);
    v += __shfl_xor(v, 4, 64); v += __shfl_xor(v, 8, 64);
    if (ln == 0) s_den[ch][rh * 16 + q * 4 + i] = v;
  }
  __syncthreads();
  if (tid < 32) {
    float dv = fmaxf(s_den[0][tid] + s_den[1][tid], 1e-12f);
    s_den[0][tid] = 1.0f / dv;                   // invden
  }
  __syncthreads();
  // ---- ||mid||^2 partials ----
#pragma unroll
  for (int rt = 0; rt < 2; ++rt)
#pragma unroll
    for (int i = 0; i < 4; ++i) {
      int s = rt * 16 + q * 4 + i;
      float inv = s_den[0][s];
      float mm = 0.f;
#pragma unroll
      for (int nt = 0; nt < 8; ++nt) {
        float mid = acc[rt][nt][i] * inv;
        mm += mid * mid;
      }
      mm += __shfl_xor(mm, 1, 64); mm += __shfl_xor(mm, 2, 64);
      mm += __shfl_xor(mm, 4, 64); mm += __shfl_xor(mm, 8, 64);
      if (ln == 0) s_mn2[w][s] = mm;
    }
  __syncthreads();
  if (tid < 32) {
    float mn2 = s_mn2[0][tid] + s_mn2[1][tid] + s_mn2[2][tid] + s_mn2[3][tid];
    float mn = sqrtf(mn2);
    float sc = (mn >= 1.0f) ? (1.0f - 1e-6f) / mn : 1.0f;
    float mn2c = fminf(mn2 * sc * sc, 1.0f - 1e-6f);
    float z0 = 1.0f / sqrtf(fmaxf(1.0f - mn2c, 1e-12f));
    float zc = fmaxf(z0, 1.0f + 1e-7f);
    float d0 = LN2_F * __builtin_amdgcn_logf(zc + __builtin_amdgcn_sqrtf(zc * zc - 1.0f));
    s_g[tid] = (d0 / fmaxf(mn, 1e-12f)) * s_den[0][tid];   // out = s_g[s] * num
  }
  __syncthreads();

  // ---- transpose 2 s-rows at a time through LDS, coalesced float4 stores ----
  float* pbuf = (float*)KA;                      // 4KB of the dead K/V buffer
  for (int sp = 0; sp < 16; ++sp) {
#pragma unroll
    for (int rt = 0; rt < 2; ++rt)
#pragma unroll
      for (int i = 0; i < 4; ++i) {
        int s = rt * 16 + q * 4 + i;
        if ((s >> 1) == sp) {
          float gg = s_g[s];
#pragma unroll
          for (int nt = 0; nt < 8; ++nt)
            pbuf[(s & 1) * 512 + w * 128 + nt * 16 + ln] = gg * acc[rt][nt][i];
        }
      }
    __syncthreads();
    {
      int row = tid >> 7, c4 = tid & 127;
      float4 vv = *(float4*)&pbuf[row * 512 + c4 * 4];
      *(float4*)&out[((size_t)(b * 2048 + s0 + sp * 2 + row)) * 512 + c4 * 4] = vv;
    }
    __syncthreads();
  }
}

// ---------------------------------------------------------------------------
// Workspace layout (bytes) — EXACTLY the proven r1/r3 envelope (67,502,080):
//   [0, 50331648)            proj f16 [49152][512]  (q rows 0.., k 16384.., v 32768..)
//   [50331648, 67108864)     xvT  f16 [8][512][2048]; first 3,145,728 B host
//                            wh f16 [1536][1024] until k_transpose_v runs
//   [67108864, 67305472)     f    f32 [49152]
//   [67305472, 67502080)     c0   f32 [49152]
// d_out (33,554,432 B) doubles as the per-part f16 X staging buffer; it is
// dead until k_attn overwrites it at the end.
// ---------------------------------------------------------------------------
extern "C" void kernel_launch(void* const* d_in, const int* in_sizes, int n_in,
                              void* d_out, int out_size, void* d_ws, size_t ws_size,
                              hipStream_t stream) {
  (void)in_sizes; (void)n_in; (void)out_size; (void)ws_size;
  const float* xq = (const float*)d_in[0];
  const float* xk = (const float*)d_in[1];
  const float* xv = (const float*)d_in[2];
  const float* wq = (const float*)d_in[3];
  const float* bq = (const float*)d_in[4];
  const float* wk = (const float*)d_in[5];
  const float* bk = (const float*)d_in[6];
  const float* wv = (const float*)d_in[7];
  const float* bv = (const float*)d_in[8];
  float* out = (float*)d_out;
  char* ws = (char*)d_ws;

  _Float16* proj = (_Float16*)(ws);
  _Float16* xvT  = (_Float16*)(ws + 50331648);
  _Float16* wh   = (_Float16*)(ws + 50331648);   // aliases xvT head; dead before
                                                 // k_transpose_v overwrites it
  float* fsc     = (float*)(ws + 67108864);
  float* c0a     = (float*)(ws + 67305472);
  _Float16* xs   = (_Float16*)d_out;             // 33.5MB scratch, dead till k_attn

  k_cvt_w<<<dim3(768), 256, 0, stream>>>(wq, wk, wv, wh);

  const float* xsrc[3] = { xq, xk, xv };
  const float* bsrc[3] = { bq, bk, bv };
  for (int p = 0; p < 3; ++p) {
    k_cvt_x<<<dim3(8192), 256, 0, stream>>>(xsrc[p], xs);
    k_proj<<<dim3(512), 256, 0, stream>>>(
        xs, wh + (size_t)p * 512 * 1024, bsrc[p], proj + (size_t)p * 16384 * 512);
  }

  k_rowstats<<<dim3(12288), 256, 0, stream>>>(proj, fsc, c0a);
  k_transpose_v<<<dim3(32, 8, 8), 256, 0, stream>>>(proj, xvT);
  k_attn<<<dim3(64, 8), 256, 0, stream>>>(proj, xvT, fsc, c0a, out);
}